// Round 1
// baseline (1053.650 us; speedup 1.0000x reference)
//
#include <hip/hip_runtime.h>
#include <math.h>

#define N_TOKENS 16384
#define D_MODEL  4096
#define NE       64      // experts
#define NC       128     // concat cols: [w_gate | w_noise]
#define BT       32      // tokens per block
#define BK       32      // k-chunk
#define BLOCK    256

__global__ void zero_ws(float* ws) {
    ws[threadIdx.x] = 0.f;   // 128 floats: [0..64) importance, [64..128) load
}

__device__ __forceinline__ float softplus_f(float x) {
    // matches jax.nn.softplus = logaddexp(x, 0), stable both tails
    return (x > 0.f) ? x + log1pf(expf(-x)) : log1pf(expf(x));
}

__global__ __launch_bounds__(BLOCK) void gate_main(
    const float* __restrict__ inp,
    const float* __restrict__ w_gate,
    const float* __restrict__ w_noise,
    const float* __restrict__ noise,
    float* __restrict__ out,   // [0,32768) indices(as float), [32768,65536) gates, [65536] loss
    float* __restrict__ ws)    // [0,64) importance, [64,128) load
{
    __shared__ float sA[BT][BK + 1];    // +1 pad: conflict-free scalar reads
    __shared__ float sB[BK][NC];        // 16 KB, float4-aligned rows
    __shared__ float sL[BT][NC + 1];    // logits; [*][64+e] later overwritten w/ stddev
    __shared__ float sN[BT][NE + 1];    // noise staging, then noisy logits
    __shared__ float sV1[BT], sV2[BT], sG0[BT], sG1[BT];
    __shared__ int   sI0[BT], sI1[BT];

    const int tid = threadIdx.x;
    const int bt0 = blockIdx.x * BT;

    // microtile: 16 col-groups(x8) x 16 row-groups(x2)
    const int tc = tid & 15;
    const int tr = tid >> 4;

    float acc[2][8];
    #pragma unroll
    for (int i = 0; i < 2; ++i)
        #pragma unroll
        for (int j = 0; j < 8; ++j) acc[i][j] = 0.f;

    // A-load mapping: 1 float4/thread (32 rows x 8 float4)
    const int a_row = tid >> 3;
    const int a_c4  = tid & 7;

    for (int k0 = 0; k0 < D_MODEL; k0 += BK) {
        // issue global loads early (overlap with previous compute tail)
        const float4 av = *(const float4*)(inp + (size_t)(bt0 + a_row) * D_MODEL + k0 + (a_c4 << 2));
        float4 bv[4];
        #pragma unroll
        for (int i = 0; i < 4; ++i) {
            const int v   = tid + (i << 8);
            const int row = v >> 5;
            const int c4  = v & 31;
            const float* src = (c4 < 16)
                ? (w_gate  + (size_t)(k0 + row) * NE + (c4 << 2))
                : (w_noise + (size_t)(k0 + row) * NE + ((c4 - 16) << 2));
            bv[i] = *(const float4*)src;
        }
        __syncthreads();  // previous iter's LDS reads done
        sA[a_row][a_c4 * 4 + 0] = av.x;
        sA[a_row][a_c4 * 4 + 1] = av.y;
        sA[a_row][a_c4 * 4 + 2] = av.z;
        sA[a_row][a_c4 * 4 + 3] = av.w;
        #pragma unroll
        for (int i = 0; i < 4; ++i) {
            const int v   = tid + (i << 8);
            const int row = v >> 5;
            const int c4  = v & 31;
            *(float4*)&sB[row][c4 << 2] = bv[i];
        }
        __syncthreads();
        #pragma unroll
        for (int kk = 0; kk < BK; ++kk) {
            const float a0 = sA[tr * 2 + 0][kk];
            const float a1 = sA[tr * 2 + 1][kk];
            const float4 b0 = *(const float4*)&sB[kk][tc * 8 + 0];
            const float4 b1 = *(const float4*)&sB[kk][tc * 8 + 4];
            acc[0][0] = fmaf(a0, b0.x, acc[0][0]);
            acc[0][1] = fmaf(a0, b0.y, acc[0][1]);
            acc[0][2] = fmaf(a0, b0.z, acc[0][2]);
            acc[0][3] = fmaf(a0, b0.w, acc[0][3]);
            acc[0][4] = fmaf(a0, b1.x, acc[0][4]);
            acc[0][5] = fmaf(a0, b1.y, acc[0][5]);
            acc[0][6] = fmaf(a0, b1.z, acc[0][6]);
            acc[0][7] = fmaf(a0, b1.w, acc[0][7]);
            acc[1][0] = fmaf(a1, b0.x, acc[1][0]);
            acc[1][1] = fmaf(a1, b0.y, acc[1][1]);
            acc[1][2] = fmaf(a1, b0.z, acc[1][2]);
            acc[1][3] = fmaf(a1, b0.w, acc[1][3]);
            acc[1][4] = fmaf(a1, b1.x, acc[1][4]);
            acc[1][5] = fmaf(a1, b1.y, acc[1][5]);
            acc[1][6] = fmaf(a1, b1.z, acc[1][6]);
            acc[1][7] = fmaf(a1, b1.w, acc[1][7]);
        }
    }

    // ---- spill logits to LDS ----
    __syncthreads();
    #pragma unroll
    for (int i = 0; i < 2; ++i)
        #pragma unroll
        for (int j = 0; j < 8; ++j)
            sL[tr * 2 + i][tc * 8 + j] = acc[i][j];

    // stage noise coalesced into sN
    for (int v = tid; v < BT * NE; v += BLOCK) {
        const int t = v >> 6, e = v & 63;
        sN[t][e] = noise[(size_t)(bt0 + t) * NE + e];
    }
    __syncthreads();

    // ---- pass 1: per-token top-3, gates, index/gate outputs ----
    if (tid < BT) {
        const int t  = tid;
        const int gt = bt0 + t;
        float v0 = -3.4e38f, v1 = -3.4e38f, v2 = -3.4e38f;
        int   i0 = 0, i1 = 0;
        #pragma unroll 4
        for (int e = 0; e < NE; ++e) {
            const float clean = sL[t][e];
            const float raw   = sL[t][NE + e];
            const float sd    = softplus_f(raw) + 0.01f;
            sL[t][NE + e] = sd;                       // keep stddev
            const float ny = fmaf(sN[t][e], sd, clean);
            sN[t][e] = ny;                            // keep noisy logit
            if (ny > v0)      { v2 = v1; v1 = v0; i1 = i0; v0 = ny; i0 = e; }
            else if (ny > v1) { v2 = v1; v1 = ny; i1 = e; }
            else if (ny > v2) { v2 = ny; }
        }
        const float e1 = expf(v1 - v0);
        const float d  = 1.f + e1;
        const float g0 = 1.f / d;
        const float g1 = e1 / d;
        out[2 * gt + 0] = (float)i0;
        out[2 * gt + 1] = (float)i1;
        out[2 * N_TOKENS + 2 * gt + 0] = g0;
        out[2 * N_TOKENS + 2 * gt + 1] = g1;
        sV1[t] = v1; sV2[t] = v2;
        sI0[t] = i0; sI1[t] = i1;
        sG0[t] = g0; sG1[t] = g1;
    }
    __syncthreads();

    // ---- pass 2: per-expert load & importance partial sums ----
    if (tid < NE) {
        const int e = tid;
        float loadsum = 0.f, impsum = 0.f;
        #pragma unroll 4
        for (int t = 0; t < BT; ++t) {
            const float clean = sL[t][e];
            const float sd    = sL[t][NE + e];
            const float ny    = sN[t][e];
            const float thr   = (ny > sV2[t]) ? sV2[t] : sV1[t];
            const float z     = (clean - thr) / sd;
            loadsum += 0.5f * erfcf(-z * 0.70710678118654752f);   // norm.cdf(z)
            if (sI0[t] == e) impsum += sG0[t];
            if (sI1[t] == e) impsum += sG1[t];
        }
        atomicAdd(&ws[e],      impsum);
        atomicAdd(&ws[NE + e], loadsum);
    }
}

__global__ void loss_k(const float* __restrict__ ws, float* __restrict__ out) {
    const int l = threadIdx.x;   // 64 threads = 1 wave
    const float x = ws[l];        // importance
    const float y = ws[NE + l];   // load
    float sx = x, sy = y;
    #pragma unroll
    for (int off = 32; off >= 1; off >>= 1) {
        sx += __shfl_xor(sx, off);
        sy += __shfl_xor(sy, off);
    }
    const float mx = sx / 64.f, my = sy / 64.f;
    const float dx = x - mx,    dy = y - my;
    float vx = dx * dx, vy = dy * dy;
    #pragma unroll
    for (int off = 32; off >= 1; off >>= 1) {
        vx += __shfl_xor(vx, off);
        vy += __shfl_xor(vy, off);
    }
    if (l == 0) {
        const float var_i = vx / 63.f, var_l = vy / 63.f;
        out[2 * N_TOKENS * 2] = var_i / (mx * mx + 1e-10f) + var_l / (my * my + 1e-10f);
    }
}

extern "C" void kernel_launch(void* const* d_in, const int* in_sizes, int n_in,
                              void* d_out, int out_size, void* d_ws, size_t ws_size,
                              hipStream_t stream) {
    const float* inp     = (const float*)d_in[0];
    const float* w_gate  = (const float*)d_in[1];
    const float* w_noise = (const float*)d_in[2];
    const float* noise   = (const float*)d_in[3];
    float* out = (float*)d_out;
    float* ws  = (float*)d_ws;

    zero_ws<<<1, 128, 0, stream>>>(ws);
    gate_main<<<N_TOKENS / BT, BLOCK, 0, stream>>>(inp, w_gate, w_noise, noise, out, ws);
    loss_k<<<1, 64, 0, stream>>>(ws, out);
}

// Round 3
// 786.610 us; speedup vs baseline: 1.3395x; 1.3395x over previous
//
#include <hip/hip_runtime.h>
#include <math.h>

#define N_TOKENS 16384
#define D_MODEL  4096
#define NE       64
#define NC       128
#define DELTA    0.02f
#define LIST_CAP 16384

// ---- ws layout (bytes) ----
#define WS_SUMS   0          // 128 f32: [0..64) importance, [64..128) load
#define WS_CNT    512        // int
#define WS_LIST   4096       // 16384 int risky-token list
#define WS_BHI    131072     // 1 MB bf16 hi limbs [128 kc][128 n][32 kk]
#define WS_BLO    1179648    // 1 MB bf16 lo limbs
#define FAST_NEED 2228224

typedef unsigned short u16;
typedef __attribute__((ext_vector_type(8))) short short8;   // 8 bf16
typedef __attribute__((ext_vector_type(4))) float f32x4;

#define MFMA16 __builtin_amdgcn_mfma_f32_16x16x32_bf16

typedef const __attribute__((address_space(1))) void cg_void;
typedef __attribute__((address_space(3))) void lds_void;
__device__ __forceinline__ void gll16(const void* g, void* l) {
    __builtin_amdgcn_global_load_lds((cg_void*)g, (lds_void*)l, 16, 0, 0);
}

__device__ __forceinline__ u16 f2bf(float x) {
    unsigned u = __float_as_uint(x);
    return (u16)((u + 0x7FFFu + ((u >> 16) & 1u)) >> 16);
}
__device__ __forceinline__ float bf2f(u16 h) { return __uint_as_float(((unsigned)h) << 16); }
__device__ __forceinline__ float softplus_f(float x) {
    return (x > 0.f) ? x + log1pf(expf(-x)) : log1pf(expf(x));
}
__device__ __forceinline__ float ncdf(float z) { return 0.5f * erfcf(-z * 0.70710678118654752f); }

__global__ void k_zero(float* __restrict__ sums, int* __restrict__ cnt) {
    if (threadIdx.x < 128) sums[threadIdx.x] = 0.f;
    if (cnt != nullptr && threadIdx.x == 128) *cnt = 0;
}

// B limbs: layout [kc][n][kk], k = kc*32 + kk, n in [0,128) = [w_gate | w_noise]
__global__ __launch_bounds__(256) void k_prep(const float* __restrict__ wg, const float* __restrict__ wn,
                                              u16* __restrict__ Bhi, u16* __restrict__ Blo) {
    __shared__ float sW[32 * 129];
    const int kc = blockIdx.x, tid = threadIdx.x;
    #pragma unroll
    for (int i = 0; i < 16; ++i) {
        const int v = tid + 256 * i;
        const int kk = v >> 7, n = v & 127;
        const int k = kc * 32 + kk;
        const float x = (n < 64) ? wg[(size_t)k * 64 + n] : wn[(size_t)k * 64 + n - 64];
        sW[kk * 129 + n] = x;
    }
    __syncthreads();
    #pragma unroll
    for (int i = 0; i < 16; ++i) {
        const int o = tid + 256 * i;          // o = n*32 + kk
        const int n = o >> 5, kk = o & 31;
        const float x = sW[kk * 129 + n];
        const u16 h = f2bf(x);
        Bhi[(size_t)kc * 4096 + o] = h;
        Blo[(size_t)kc * 4096 + o] = f2bf(x - bf2f(h));
    }
}

// Fused split-bf16 GEMM + gating epilogue. 32 tokens/block, full K, 4 waves:
// wave w: rows r0=(w&1)*16, cols c0=(w>>1)*64 of the 32x128 logits tile.
__global__ __launch_bounds__(256, 2) void k_main(
    const float* __restrict__ inp, const u16* __restrict__ Bhi, const u16* __restrict__ Blo,
    const float* __restrict__ noise, float* __restrict__ out, float* __restrict__ sums,
    int* __restrict__ cnt, int* __restrict__ list)
{
    __shared__ __align__(16) char smem[26496];
    u16* const sAh = (u16*)(smem);            // [32][32] bf16 hi
    u16* const sAl = (u16*)(smem + 2048);     // lo
    u16* const sBh = (u16*)(smem + 4096);     // [128][32]
    u16* const sBl = (u16*)(smem + 12288);

    const int tid = threadIdx.x;
    const int l   = tid & 63;
    const int w   = tid >> 6;
    const int t0  = blockIdx.x * 32;
    const int m   = l & 15;
    const int kg  = l >> 4;
    const int r0  = (w & 1) * 16;
    const int c0  = (w >> 1) * 64;

    f32x4 acc[4];
    #pragma unroll
    for (int j = 0; j < 4; ++j)
        #pragma unroll
        for (int r = 0; r < 4; ++r) acc[j][r] = 0.f;

    const int arow = tid >> 3, ac4 = tid & 7;       // 32 rows x 8 float4
    const float* aptr = inp + (size_t)(t0 + arow) * D_MODEL + ac4 * 4;

    for (int c = 0; c < 128; ++c) {
        const float4 av = *(const float4*)aptr;
        aptr += 32;

        __syncthreads();   // previous iter's frag reads done

        #pragma unroll
        for (int j = 0; j < 2; ++j) {
            const size_t eo = (size_t)c * 4096 + w * 1024 + j * 512 + l * 8;
            gll16(Bhi + eo, smem + 4096  + w * 2048 + j * 1024);
            gll16(Blo + eo, smem + 12288 + w * 2048 + j * 1024);
        }

        {   // A limbs: hi = truncate, lo = RTNE(residual)
            const float xs[4] = {av.x, av.y, av.z, av.w};
            u16 hh[4], ll[4];
            #pragma unroll
            for (int q = 0; q < 4; ++q) {
                const unsigned u = __float_as_uint(xs[q]);
                hh[q] = (u16)(u >> 16);
                ll[q] = f2bf(xs[q] - __uint_as_float(u & 0xFFFF0000u));
            }
            uint2 ph, pl;
            ph.x = (unsigned)hh[0] | ((unsigned)hh[1] << 16);
            ph.y = (unsigned)hh[2] | ((unsigned)hh[3] << 16);
            pl.x = (unsigned)ll[0] | ((unsigned)ll[1] << 16);
            pl.y = (unsigned)ll[2] | ((unsigned)ll[3] << 16);
            *(uint2*)&sAh[arow * 32 + ac4 * 4] = ph;
            *(uint2*)&sAl[arow * 32 + ac4 * 4] = pl;
        }

        __syncthreads();   // drains vmcnt (B in LDS) + lgkm (A in LDS)

        const short8 ah = *(const short8*)&sAh[(r0 + m) * 32 + kg * 8];
        const short8 al = *(const short8*)&sAl[(r0 + m) * 32 + kg * 8];
        #pragma unroll
        for (int j = 0; j < 4; ++j) {
            const short8 bh = *(const short8*)&sBh[(c0 + j * 16 + m) * 32 + kg * 8];
            const short8 bl = *(const short8*)&sBl[(c0 + j * 16 + m) * 32 + kg * 8];
            acc[j] = MFMA16(ah, bh, acc[j], 0, 0, 0);
            acc[j] = MFMA16(ah, bl, acc[j], 0, 0, 0);
            acc[j] = MFMA16(al, bh, acc[j], 0, 0, 0);
        }
    }
    __syncthreads();   // GEMM LDS dead; overlay epilogue arrays

    float* const sL  = (float*)(smem);          // [32][132]
    float* const sN  = (float*)(smem + 16896);  // [32][68]
    float* const sV1 = (float*)(smem + 25600);
    float* const sV2 = (float*)(smem + 25728);
    float* const sG0 = (float*)(smem + 25856);
    float* const sG1 = (float*)(smem + 25984);
    int*   const sI0 = (int*)(smem + 26112);
    int*   const sI1 = (int*)(smem + 26240);
    int*   const sRk = (int*)(smem + 26368);

    // C/D layout (m89-verified): col = lane&15, row = (lane>>4)*4 + reg
    #pragma unroll
    for (int j = 0; j < 4; ++j)
        #pragma unroll
        for (int r = 0; r < 4; ++r)
            sL[(r0 + kg * 4 + r) * 132 + c0 + j * 16 + m] = acc[j][r];

    #pragma unroll
    for (int i = 0; i < 2; ++i) {
        const int v = tid + 256 * i;            // 512 float4
        const int t = v >> 4, e4 = v & 15;
        *(float4*)&sN[t * 68 + e4 * 4] = *(const float4*)(noise + (size_t)(t0 + t) * NE + e4 * 4);
    }
    __syncthreads();

    if (tid < 32) {
        const int t = tid, gt = t0 + t;
        float v0 = -3.4e38f, v1 = -3.4e38f, v2 = -3.4e38f;
        int i0 = 0, i1 = 0;
        #pragma unroll 4
        for (int e = 0; e < NE; ++e) {
            const float clean = sL[t * 132 + e];
            const float sd    = softplus_f(sL[t * 132 + 64 + e]) + 0.01f;
            const float ny    = fmaf(sN[t * 68 + e], sd, clean);
            if (ny > v0)      { v2 = v1; v1 = v0; i1 = i0; v0 = ny; i0 = e; }
            else if (ny > v1) { v2 = v1; v1 = ny; i1 = e; }
            else if (ny > v2) { v2 = ny; }
        }
        const float e1 = expf(v1 - v0);
        const float d  = 1.f + e1;
        const float g0 = 1.f / d, g1 = e1 / d;
        out[2 * gt + 0] = (float)i0;
        out[2 * gt + 1] = (float)i1;
        out[2 * N_TOKENS + 2 * gt + 0] = g0;
        out[2 * N_TOKENS + 2 * gt + 1] = g1;
        const int risky = ((v0 - v1) < DELTA) || ((v1 - v2) < DELTA);
        sRk[t] = risky;
        if (risky) {
            const int idx = atomicAdd(cnt, 1);
            if (idx < LIST_CAP) list[idx] = gt;
        }
        sV1[t] = v1; sV2[t] = v2; sI0[t] = i0; sI1[t] = i1; sG0[t] = g0; sG1[t] = g1;
    }
    __syncthreads();

    if (tid < 128) {
        const int e = tid & 63, h = tid >> 6;
        float loadsum = 0.f, impsum = 0.f;
        #pragma unroll 4
        for (int t = h * 16; t < h * 16 + 16; ++t) {
            if (sRk[t]) continue;
            const float clean = sL[t * 132 + e];
            const float sd    = softplus_f(sL[t * 132 + 64 + e]) + 0.01f;
            const float ny    = fmaf(sN[t * 68 + e], sd, clean);
            const float thr   = (ny > sV2[t]) ? sV2[t] : sV1[t];
            loadsum += ncdf((clean - thr) / sd);
            if (sI0[t] == e) impsum += sG0[t];
            if (sI1[t] == e) impsum += sG1[t];
        }
        atomicAdd(&sums[e], impsum);
        atomicAdd(&sums[64 + e], loadsum);
    }
}

// exact fp32 recompute for risky (near-tie) tokens
__global__ __launch_bounds__(256) void k_fix(const float* __restrict__ inp,
                                             const float* __restrict__ wg,
                                             const float* __restrict__ wn,
                                             const float* __restrict__ noise,
                                             float* __restrict__ out,
                                             float* __restrict__ sums,
                                             const int* __restrict__ cnt,
                                             const int* __restrict__ list) {
    __shared__ float sRow[D_MODEL];
    __shared__ float sP[256];
    __shared__ float sLg[NC];
    __shared__ float fv1, fv2;

    const int tid = threadIdx.x;
    int n = *cnt;
    if (n > LIST_CAP) n = LIST_CAP;

    for (int it = blockIdx.x; it < n; it += gridDim.x) {
        const int tok = list[it];
        __syncthreads();
        #pragma unroll
        for (int i = 0; i < 4; ++i)
            *(float4*)&sRow[(tid + 256 * i) * 4] = *(const float4*)(inp + (size_t)tok * D_MODEL + (tid + 256 * i) * 4);
        __syncthreads();

        const int c = tid & 127, h = tid >> 7;
        const float* wcol = (c < 64) ? (wg + c) : (wn + c - 64);
        float s = 0.f;
        #pragma unroll 8
        for (int k = h * 2048; k < h * 2048 + 2048; ++k)
            s = fmaf(sRow[k], wcol[(size_t)k * 64], s);
        sP[tid] = s;
        __syncthreads();
        if (tid < 128) sLg[tid] = sP[tid] + sP[tid + 128];
        __syncthreads();

        if (tid == 0) {
            float v0 = -3.4e38f, v1 = -3.4e38f, v2 = -3.4e38f;
            int i0 = 0, i1 = 0;
            for (int e = 0; e < NE; ++e) {
                const float sd = softplus_f(sLg[64 + e]) + 0.01f;
                const float ny = fmaf(noise[(size_t)tok * NE + e], sd, sLg[e]);
                if (ny > v0)      { v2 = v1; v1 = v0; i1 = i0; v0 = ny; i0 = e; }
                else if (ny > v1) { v2 = v1; v1 = ny; i1 = e; }
                else if (ny > v2) { v2 = ny; }
            }
            const float e1 = expf(v1 - v0);
            const float d  = 1.f + e1;
            const float g0 = 1.f / d, g1 = e1 / d;
            out[2 * tok + 0] = (float)i0;
            out[2 * tok + 1] = (float)i1;
            out[2 * N_TOKENS + 2 * tok + 0] = g0;
            out[2 * N_TOKENS + 2 * tok + 1] = g1;
            atomicAdd(&sums[i0], g0);
            atomicAdd(&sums[i1], g1);
            fv1 = v1; fv2 = v2;
        }
        __syncthreads();
        if (tid < 64) {
            const int e = tid;
            const float clean = sLg[e];
            const float sd    = softplus_f(sLg[64 + e]) + 0.01f;
            const float ny    = fmaf(noise[(size_t)tok * NE + e], sd, clean);
            const float thr   = (ny > fv2) ? fv2 : fv1;
            atomicAdd(&sums[64 + e], ncdf((clean - thr) / sd));
        }
    }
}

__global__ void k_loss(const float* __restrict__ sums, float* __restrict__ out) {
    const int l = threadIdx.x;
    const float x = sums[l];
    const float y = sums[64 + l];
    float sx = x, sy = y;
    #pragma unroll
    for (int off = 32; off >= 1; off >>= 1) { sx += __shfl_xor(sx, off); sy += __shfl_xor(sy, off); }
    const float mx = sx / 64.f, my = sy / 64.f;
    const float dx = x - mx, dy = y - my;
    float vx = dx * dx, vy = dy * dy;
    #pragma unroll
    for (int off = 32; off >= 1; off >>= 1) { vx += __shfl_xor(vx, off); vy += __shfl_xor(vy, off); }
    if (l == 0)
        out[2 * N_TOKENS * 2] = (vx / 63.f) / (mx * mx + 1e-10f) + (vy / 63.f) / (my * my + 1e-10f);
}

// ---------- fallback: round-1 kernel, verbatim (uses only 512 B of ws) ----------
#define BT 32
#define BK 32
#define FBLOCK 256
__global__ __launch_bounds__(FBLOCK) void gate_fb(
    const float* __restrict__ inp, const float* __restrict__ w_gate,
    const float* __restrict__ w_noise, const float* __restrict__ noise,
    float* __restrict__ out, float* __restrict__ ws)
{
    __shared__ float sA[BT][BK + 1];
    __shared__ float sB[BK][NC];
    __shared__ float sL[BT][NC + 1];
    __shared__ float sN[BT][NE + 1];
    __shared__ float sV1[BT], sV2[BT], sG0[BT], sG1[BT];
    __shared__ int   sI0[BT], sI1[BT];

    const int tid = threadIdx.x;
    const int bt0 = blockIdx.x * BT;
    const int tc = tid & 15;
    const int tr = tid >> 4;

    float acc[2][8];
    #pragma unroll
    for (int i = 0; i < 2; ++i)
        #pragma unroll
        for (int j = 0; j < 8; ++j) acc[i][j] = 0.f;

    const int a_row = tid >> 3;
    const int a_c4  = tid & 7;

    for (int k0 = 0; k0 < D_MODEL; k0 += BK) {
        const float4 av = *(const float4*)(inp + (size_t)(bt0 + a_row) * D_MODEL + k0 + (a_c4 << 2));
        float4 bv[4];
        #pragma unroll
        for (int i = 0; i < 4; ++i) {
            const int v   = tid + (i << 8);
            const int row = v >> 5;
            const int c4  = v & 31;
            const float* src = (c4 < 16)
                ? (w_gate  + (size_t)(k0 + row) * NE + (c4 << 2))
                : (w_noise + (size_t)(k0 + row) * NE + ((c4 - 16) << 2));
            bv[i] = *(const float4*)src;
        }
        __syncthreads();
        sA[a_row][a_c4 * 4 + 0] = av.x;
        sA[a_row][a_c4 * 4 + 1] = av.y;
        sA[a_row][a_c4 * 4 + 2] = av.z;
        sA[a_row][a_c4 * 4 + 3] = av.w;
        #pragma unroll
        for (int i = 0; i < 4; ++i) {
            const int v   = tid + (i << 8);
            const int row = v >> 5;
            const int c4  = v & 31;
            *(float4*)&sB[row][c4 << 2] = bv[i];
        }
        __syncthreads();
        #pragma unroll
        for (int kk = 0; kk < BK; ++kk) {
            const float a0 = sA[tr * 2 + 0][kk];
            const float a1 = sA[tr * 2 + 1][kk];
            const float4 b0 = *(const float4*)&sB[kk][tc * 8 + 0];
            const float4 b1 = *(const float4*)&sB[kk][tc * 8 + 4];
            acc[0][0] = fmaf(a0, b0.x, acc[0][0]); acc[0][1] = fmaf(a0, b0.y, acc[0][1]);
            acc[0][2] = fmaf(a0, b0.z, acc[0][2]); acc[0][3] = fmaf(a0, b0.w, acc[0][3]);
            acc[0][4] = fmaf(a0, b1.x, acc[0][4]); acc[0][5] = fmaf(a0, b1.y, acc[0][5]);
            acc[0][6] = fmaf(a0, b1.z, acc[0][6]); acc[0][7] = fmaf(a0, b1.w, acc[0][7]);
            acc[1][0] = fmaf(a1, b0.x, acc[1][0]); acc[1][1] = fmaf(a1, b0.y, acc[1][1]);
            acc[1][2] = fmaf(a1, b0.z, acc[1][2]); acc[1][3] = fmaf(a1, b0.w, acc[1][3]);
            acc[1][4] = fmaf(a1, b1.x, acc[1][4]); acc[1][5] = fmaf(a1, b1.y, acc[1][5]);
            acc[1][6] = fmaf(a1, b1.z, acc[1][6]); acc[1][7] = fmaf(a1, b1.w, acc[1][7]);
        }
    }

    __syncthreads();
    #pragma unroll
    for (int i = 0; i < 2; ++i)
        #pragma unroll
        for (int j = 0; j < 8; ++j)
            sL[tr * 2 + i][tc * 8 + j] = acc[i][j];

    for (int v = tid; v < BT * NE; v += FBLOCK) {
        const int t = v >> 6, e = v & 63;
        sN[t][e] = noise[(size_t)(bt0 + t) * NE + e];
    }
    __syncthreads();

    if (tid < BT) {
        const int t  = tid;
        const int gt = bt0 + t;
        float v0 = -3.4e38f, v1 = -3.4e38f, v2 = -3.4e38f;
        int   i0 = 0, i1 = 0;
        #pragma unroll 4
        for (int e = 0; e < NE; ++e) {
            const float clean = sL[t][e];
            const float raw   = sL[t][NE + e];
            const float sd    = softplus_f(raw) + 0.01f;
            sL[t][NE + e] = sd;
            const float ny = fmaf(sN[t][e], sd, clean);
            sN[t][e] = ny;
            if (ny > v0)      { v2 = v1; v1 = v0; i1 = i0; v0 = ny; i0 = e; }
            else if (ny > v1) { v2 = v1; v1 = ny; i1 = e; }
            else if (ny > v2) { v2 = ny; }
        }
        const float e1 = expf(v1 - v0);
        const float d  = 1.f + e1;
        const float g0 = 1.f / d;
        const float g1 = e1 / d;
        out[2 * gt + 0] = (float)i0;
        out[2 * gt + 1] = (float)i1;
        out[2 * N_TOKENS + 2 * gt + 0] = g0;
        out[2 * N_TOKENS + 2 * gt + 1] = g1;
        sV1[t] = v1; sV2[t] = v2;
        sI0[t] = i0; sI1[t] = i1;
        sG0[t] = g0; sG1[t] = g1;
    }
    __syncthreads();

    if (tid < NE) {
        const int e = tid;
        float loadsum = 0.f, impsum = 0.f;
        #pragma unroll 4
        for (int t = 0; t < BT; ++t) {
            const float clean = sL[t][e];
            const float sd    = sL[t][NE + e];
            const float ny    = sN[t][e];
            const float thr   = (ny > sV2[t]) ? sV2[t] : sV1[t];
            const float z     = (clean - thr) / sd;
            loadsum += ncdf(z);
            if (sI0[t] == e) impsum += sG0[t];
            if (sI1[t] == e) impsum += sG1[t];
        }
        atomicAdd(&ws[e],      impsum);
        atomicAdd(&ws[NE + e], loadsum);
    }
}

extern "C" void kernel_launch(void* const* d_in, const int* in_sizes, int n_in,
                              void* d_out, int out_size, void* d_ws, size_t ws_size,
                              hipStream_t stream) {
    const float* inp     = (const float*)d_in[0];
    const float* w_gate  = (const float*)d_in[1];
    const float* w_noise = (const float*)d_in[2];
    const float* noise   = (const float*)d_in[3];
    float* out = (float*)d_out;

    float* sums = (float*)((char*)d_ws + WS_SUMS);
    int*   cnt  = (int*)((char*)d_ws + WS_CNT);
    int*   list = (int*)((char*)d_ws + WS_LIST);
    u16*   Bhi  = (u16*)((char*)d_ws + WS_BHI);
    u16*   Blo  = (u16*)((char*)d_ws + WS_BLO);

    if (ws_size >= (size_t)FAST_NEED) {
        k_zero<<<1, 192, 0, stream>>>(sums, cnt);
        k_prep<<<128, 256, 0, stream>>>(w_gate, w_noise, Bhi, Blo);
        k_main<<<N_TOKENS / 32, 256, 0, stream>>>(inp, Bhi, Blo, noise, out, sums, cnt, list);
        k_fix<<<128, 256, 0, stream>>>(inp, w_gate, w_noise, noise, out, sums, cnt, list);
        k_loss<<<1, 64, 0, stream>>>(sums, out);
    } else {
        k_zero<<<1, 192, 0, stream>>>(sums, nullptr);
        gate_fb<<<N_TOKENS / BT, FBLOCK, 0, stream>>>(inp, w_gate, w_noise, noise, out, sums);
        k_loss<<<1, 64, 0, stream>>>(sums, out);
    }
}

// Round 4
// 571.211 us; speedup vs baseline: 1.8446x; 1.3771x over previous
//
#include <hip/hip_runtime.h>
#include <math.h>

#define N_TOKENS 16384
#define D_MODEL  4096
#define NE       64
#define NC       128
#define DELTA    0.005f
#define LIST_CAP 16384

// ---- ws layout (bytes) ---- (unchanged from round 3; ws_size >= FAST_NEED proven)
#define WS_SUMS   0          // 128 f32: [0..64) importance, [64..128) load
#define WS_CNT    512        // int
#define WS_LIST   4096       // 16384 int risky-token list
#define WS_BHI    131072     // 1 MB bf16 hi limbs [128 kc][128 n][32 kk]
#define WS_BLO    1179648    // 1 MB bf16 lo limbs
#define FAST_NEED 2228224

typedef unsigned short u16;
typedef __attribute__((ext_vector_type(8))) short short8;   // 8 bf16
typedef __attribute__((ext_vector_type(4))) float f32x4;

#define MFMA16 __builtin_amdgcn_mfma_f32_16x16x32_bf16

typedef const __attribute__((address_space(1))) void cg_void;
typedef __attribute__((address_space(3))) void lds_void;
__device__ __forceinline__ void gll16(const void* g, void* l) {
    __builtin_amdgcn_global_load_lds((cg_void*)g, (lds_void*)l, 16, 0, 0);
}

__device__ __forceinline__ u16 f2bf(float x) {
    unsigned u = __float_as_uint(x);
    return (u16)((u + 0x7FFFu + ((u >> 16) & 1u)) >> 16);
}
__device__ __forceinline__ float bf2f(u16 h) { return __uint_as_float(((unsigned)h) << 16); }
__device__ __forceinline__ float softplus_f(float x) {
    return (x > 0.f) ? x + log1pf(expf(-x)) : log1pf(expf(x));
}
__device__ __forceinline__ float ncdf(float z) { return 0.5f * erfcf(-z * 0.70710678118654752f); }

__global__ void k_zero(float* __restrict__ sums, int* __restrict__ cnt) {
    if (threadIdx.x < 128) sums[threadIdx.x] = 0.f;
    if (cnt != nullptr && threadIdx.x == 128) *cnt = 0;
}

// B limbs: layout [kc][n][kk], k = kc*32 + kk, n in [0,128) = [w_gate | w_noise]
__global__ __launch_bounds__(256) void k_prep(const float* __restrict__ wg, const float* __restrict__ wn,
                                              u16* __restrict__ Bhi, u16* __restrict__ Blo) {
    __shared__ float sW[32 * 129];
    const int kc = blockIdx.x, tid = threadIdx.x;
    #pragma unroll
    for (int i = 0; i < 16; ++i) {
        const int v = tid + 256 * i;
        const int kk = v >> 7, n = v & 127;
        const int k = kc * 32 + kk;
        const float x = (n < 64) ? wg[(size_t)k * 64 + n] : wn[(size_t)k * 64 + n - 64];
        sW[kk * 129 + n] = x;
    }
    __syncthreads();
    #pragma unroll
    for (int i = 0; i < 16; ++i) {
        const int o = tid + 256 * i;          // o = n*32 + kk
        const int n = o >> 5, kk = o & 31;
        const float x = sW[kk * 129 + n];
        const u16 h = f2bf(x);
        Bhi[(size_t)kc * 4096 + o] = h;
        Blo[(size_t)kc * 4096 + o] = f2bf(x - bf2f(h));
    }
}

// Fused split-bf16 GEMM + gating epilogue.
// 64 tokens/block, 512 thr = 8 waves, wave w: rows (w&1)*32..+32, cols (w>>1)*32..+32.
// Single-barrier double-buffered K-loop (BK=32, 128 chunks).
__global__ __launch_bounds__(512, 2) void k_main(
    const float* __restrict__ inp, const u16* __restrict__ Bhi, const u16* __restrict__ Blo,
    const float* __restrict__ noise, float* __restrict__ out, float* __restrict__ sums,
    int* __restrict__ cnt, int* __restrict__ list)
{
    __shared__ __align__(16) char smem[53248];
    // buffer b (b=0,1) at smem + b*24576:
    //   sAh [64][32] u16 @ +0      (4 KB)
    //   sAl            @ +4096
    //   sBh [128][32]  @ +8192     (8 KB)
    //   sBl            @ +16384

    const int tid = threadIdx.x;
    const int l   = tid & 63;
    const int w   = tid >> 6;         // 0..7
    const int t0  = blockIdx.x * 64;
    const int m   = l & 15;
    const int kg  = l >> 4;
    const int rg  = (w & 1) * 32;     // wave row base
    const int cg  = (w >> 1) * 32;    // wave col base

    f32x4 acc[2][2];
    #pragma unroll
    for (int i = 0; i < 2; ++i)
        #pragma unroll
        for (int j = 0; j < 2; ++j)
            #pragma unroll
            for (int r = 0; r < 4; ++r) acc[i][j][r] = 0.f;

    const int arow = tid >> 3, ac4 = tid & 7;       // 64 rows x 8 float4, 1 per thread
    const float* aptr = inp + (size_t)(t0 + arow) * D_MODEL + ac4 * 4;

    // ---- helpers as macros over buffer base ----
#define ABUF(b)  ((u16*)(smem + (b) * 24576))
#define ALBUF(b) ((u16*)(smem + (b) * 24576 + 4096))
#define BHLDS(b) (smem + (b) * 24576 + 8192)
#define BLLDS(b) (smem + (b) * 24576 + 16384)

    // prologue: stage chunk 0 into buffer 0
    {
        const float4 av = *(const float4*)aptr;
        const size_t eo = (size_t)w * 512 + l * 8;            // chunk 0
        gll16(Bhi + eo, BHLDS(0) + w * 1024);
        gll16(Blo + eo, BLLDS(0) + w * 1024);
        const float xs[4] = {av.x, av.y, av.z, av.w};
        u16 hh[4], ll[4];
        #pragma unroll
        for (int q = 0; q < 4; ++q) {
            const unsigned u = __float_as_uint(xs[q]);
            hh[q] = (u16)(u >> 16);
            ll[q] = f2bf(xs[q] - __uint_as_float(u & 0xFFFF0000u));
        }
        uint2 ph, pl;
        ph.x = (unsigned)hh[0] | ((unsigned)hh[1] << 16);
        ph.y = (unsigned)hh[2] | ((unsigned)hh[3] << 16);
        pl.x = (unsigned)ll[0] | ((unsigned)ll[1] << 16);
        pl.y = (unsigned)ll[2] | ((unsigned)ll[3] << 16);
        *(uint2*)&ABUF(0)[arow * 32 + ac4 * 4] = ph;
        *(uint2*)&ALBUF(0)[arow * 32 + ac4 * 4] = pl;
    }

    for (int c = 0; c < 128; ++c) {
        const int rc = c & 1, nb = rc ^ 1;
        __syncthreads();   // drains vmcnt+lgkm: buffer rc complete; prev reads of nb done

        float4 avn;
        if (c < 127) {
            avn = *(const float4*)(aptr + (c + 1) * 32);
            const size_t eo = (size_t)(c + 1) * 4096 + w * 512 + l * 8;
            gll16(Bhi + eo, BHLDS(nb) + w * 1024);
            gll16(Blo + eo, BLLDS(nb) + w * 1024);
        }

        const u16* sAh = ABUF(rc);
        const u16* sAl = ALBUF(rc);
        const u16* sBh = (const u16*)BHLDS(rc);
        const u16* sBl = (const u16*)BLLDS(rc);

        short8 ah[2], al[2], bh[2], bl[2];
        #pragma unroll
        for (int i = 0; i < 2; ++i) {
            ah[i] = *(const short8*)&sAh[(rg + i * 16 + m) * 32 + kg * 8];
            al[i] = *(const short8*)&sAl[(rg + i * 16 + m) * 32 + kg * 8];
        }
        #pragma unroll
        for (int j = 0; j < 2; ++j) {
            bh[j] = *(const short8*)&sBh[(cg + j * 16 + m) * 32 + kg * 8];
            bl[j] = *(const short8*)&sBl[(cg + j * 16 + m) * 32 + kg * 8];
        }
        #pragma unroll
        for (int i = 0; i < 2; ++i)
            #pragma unroll
            for (int j = 0; j < 2; ++j) {
                acc[i][j] = MFMA16(ah[i], bh[j], acc[i][j], 0, 0, 0);
                acc[i][j] = MFMA16(ah[i], bl[j], acc[i][j], 0, 0, 0);
                acc[i][j] = MFMA16(al[i], bh[j], acc[i][j], 0, 0, 0);
            }

        if (c < 127) {
            const float xs[4] = {avn.x, avn.y, avn.z, avn.w};
            u16 hh[4], ll[4];
            #pragma unroll
            for (int q = 0; q < 4; ++q) {
                const unsigned u = __float_as_uint(xs[q]);
                hh[q] = (u16)(u >> 16);
                ll[q] = f2bf(xs[q] - __uint_as_float(u & 0xFFFF0000u));
            }
            uint2 ph, pl;
            ph.x = (unsigned)hh[0] | ((unsigned)hh[1] << 16);
            ph.y = (unsigned)hh[2] | ((unsigned)hh[3] << 16);
            pl.x = (unsigned)ll[0] | ((unsigned)ll[1] << 16);
            pl.y = (unsigned)ll[2] | ((unsigned)ll[3] << 16);
            *(uint2*)&ABUF(nb)[arow * 32 + ac4 * 4] = ph;
            *(uint2*)&ALBUF(nb)[arow * 32 + ac4 * 4] = pl;
        }
    }
    __syncthreads();   // GEMM LDS dead; overlay epilogue arrays

    float* const sL  = (float*)(smem);          // [64][132] = 33792 B
    float* const sN  = (float*)(smem + 33792);  // [64][68]  = 17408 B
    float* const sV1 = (float*)(smem + 51200);
    float* const sV2 = (float*)(smem + 51456);
    float* const sG0 = (float*)(smem + 51712);
    float* const sG1 = (float*)(smem + 51968);
    int*   const sI0 = (int*)(smem + 52224);
    int*   const sI1 = (int*)(smem + 52480);
    int*   const sRk = (int*)(smem + 52736);

    // C/D layout (m89-verified): col = lane&15, row = (lane>>4)*4 + reg
    #pragma unroll
    for (int i = 0; i < 2; ++i)
        #pragma unroll
        for (int j = 0; j < 2; ++j)
            #pragma unroll
            for (int r = 0; r < 4; ++r)
                sL[(rg + i * 16 + kg * 4 + r) * 132 + cg + j * 16 + m] = acc[i][j][r];

    #pragma unroll
    for (int i = 0; i < 2; ++i) {
        const int v = tid + 512 * i;            // 1024 float4
        const int t = v >> 4, e4 = v & 15;
        *(float4*)&sN[t * 68 + e4 * 4] = *(const float4*)(noise + (size_t)(t0 + t) * NE + e4 * 4);
    }
    __syncthreads();

    if (tid < 64) {
        const int t = tid, gt = t0 + t;
        float v0 = -3.4e38f, v1 = -3.4e38f, v2 = -3.4e38f;
        int i0 = 0, i1 = 0;
        #pragma unroll 4
        for (int e = 0; e < NE; ++e) {
            const float clean = sL[t * 132 + e];
            const float sd    = softplus_f(sL[t * 132 + 64 + e]) + 0.01f;
            const float ny    = fmaf(sN[t * 68 + e], sd, clean);
            if (ny > v0)      { v2 = v1; v1 = v0; i1 = i0; v0 = ny; i0 = e; }
            else if (ny > v1) { v2 = v1; v1 = ny; i1 = e; }
            else if (ny > v2) { v2 = ny; }
        }
        const float e1 = expf(v1 - v0);
        const float d  = 1.f + e1;
        const float g0 = 1.f / d, g1 = e1 / d;
        out[2 * gt + 0] = (float)i0;
        out[2 * gt + 1] = (float)i1;
        out[2 * N_TOKENS + 2 * gt + 0] = g0;
        out[2 * N_TOKENS + 2 * gt + 1] = g1;
        const int risky = ((v0 - v1) < DELTA) || ((v1 - v2) < DELTA);
        sRk[t] = risky;
        if (risky) {
            const int idx = atomicAdd(cnt, 1);
            if (idx < LIST_CAP) list[idx] = gt;
        }
        sV1[t] = v1; sV2[t] = v2; sI0[t] = i0; sI1[t] = i1; sG0[t] = g0; sG1[t] = g1;
    }
    __syncthreads();

    if (tid < 128) {
        const int e = tid & 63, h = tid >> 6;
        float loadsum = 0.f, impsum = 0.f;
        #pragma unroll 4
        for (int t = h * 32; t < h * 32 + 32; ++t) {
            if (sRk[t]) continue;
            const float clean = sL[t * 132 + e];
            const float sd    = softplus_f(sL[t * 132 + 64 + e]) + 0.01f;
            const float ny    = fmaf(sN[t * 68 + e], sd, clean);
            const float thr   = (ny > sV2[t]) ? sV2[t] : sV1[t];
            loadsum += ncdf((clean - thr) / sd);
            if (sI0[t] == e) impsum += sG0[t];
            if (sI1[t] == e) impsum += sG1[t];
        }
        atomicAdd(&sums[e], impsum);
        atomicAdd(&sums[64 + e], loadsum);
    }
}

// exact fp32 recompute for risky (near-tie) tokens; 512 thr, K split x4
__global__ __launch_bounds__(512) void k_fix(const float* __restrict__ inp,
                                             const float* __restrict__ wg,
                                             const float* __restrict__ wn,
                                             const float* __restrict__ noise,
                                             float* __restrict__ out,
                                             float* __restrict__ sums,
                                             const int* __restrict__ cnt,
                                             const int* __restrict__ list) {
    __shared__ float sRow[D_MODEL];
    __shared__ float sP[512];
    __shared__ float sLg[NC];
    __shared__ float fv1, fv2;

    const int tid = threadIdx.x;
    int n = *cnt;
    if (n > LIST_CAP) n = LIST_CAP;

    for (int it = blockIdx.x; it < n; it += gridDim.x) {
        const int tok = list[it];
        __syncthreads();
        #pragma unroll
        for (int i = 0; i < 2; ++i)
            *(float4*)&sRow[(tid + 512 * i) * 4] = *(const float4*)(inp + (size_t)tok * D_MODEL + (tid + 512 * i) * 4);
        __syncthreads();

        const int c = tid & 127, h = tid >> 7;      // h in 0..3
        const float* wcol = (c < 64) ? (wg + c) : (wn + c - 64);
        float s = 0.f;
        #pragma unroll 16
        for (int k = h * 1024; k < h * 1024 + 1024; ++k)
            s = fmaf(sRow[k], wcol[(size_t)k * 64], s);
        sP[tid] = s;
        __syncthreads();
        if (tid < 128) sLg[tid] = sP[tid] + sP[tid + 128] + sP[tid + 256] + sP[tid + 384];
        __syncthreads();

        if (tid == 0) {
            float v0 = -3.4e38f, v1 = -3.4e38f, v2 = -3.4e38f;
            int i0 = 0, i1 = 0;
            for (int e = 0; e < NE; ++e) {
                const float sd = softplus_f(sLg[64 + e]) + 0.01f;
                const float ny = fmaf(noise[(size_t)tok * NE + e], sd, sLg[e]);
                if (ny > v0)      { v2 = v1; v1 = v0; i1 = i0; v0 = ny; i0 = e; }
                else if (ny > v1) { v2 = v1; v1 = ny; i1 = e; }
                else if (ny > v2) { v2 = ny; }
            }
            const float e1 = expf(v1 - v0);
            const float d  = 1.f + e1;
            const float g0 = 1.f / d, g1 = e1 / d;
            out[2 * tok + 0] = (float)i0;
            out[2 * tok + 1] = (float)i1;
            out[2 * N_TOKENS + 2 * tok + 0] = g0;
            out[2 * N_TOKENS + 2 * tok + 1] = g1;
            atomicAdd(&sums[i0], g0);
            atomicAdd(&sums[i1], g1);
            fv1 = v1; fv2 = v2;
        }
        __syncthreads();
        if (tid < 64) {
            const int e = tid;
            const float clean = sLg[e];
            const float sd    = softplus_f(sLg[64 + e]) + 0.01f;
            const float ny    = fmaf(noise[(size_t)tok * NE + e], sd, clean);
            const float thr   = (ny > fv2) ? fv2 : fv1;
            atomicAdd(&sums[64 + e], ncdf((clean - thr) / sd));
        }
    }
}

__global__ void k_loss(const float* __restrict__ sums, float* __restrict__ out) {
    const int l = threadIdx.x;
    const float x = sums[l];
    const float y = sums[64 + l];
    float sx = x, sy = y;
    #pragma unroll
    for (int off = 32; off >= 1; off >>= 1) { sx += __shfl_xor(sx, off); sy += __shfl_xor(sy, off); }
    const float mx = sx / 64.f, my = sy / 64.f;
    const float dx = x - mx, dy = y - my;
    float vx = dx * dx, vy = dy * dy;
    #pragma unroll
    for (int off = 32; off >= 1; off >>= 1) { vx += __shfl_xor(vx, off); vy += __shfl_xor(vy, off); }
    if (l == 0)
        out[2 * N_TOKENS * 2] = (vx / 63.f) / (mx * mx + 1e-10f) + (vy / 63.f) / (my * my + 1e-10f);
}

// ---------- fallback: round-1 kernel, verbatim (uses only 512 B of ws) ----------
#define BT 32
#define BK 32
#define FBLOCK 256
__global__ __launch_bounds__(FBLOCK) void gate_fb(
    const float* __restrict__ inp, const float* __restrict__ w_gate,
    const float* __restrict__ w_noise, const float* __restrict__ noise,
    float* __restrict__ out, float* __restrict__ ws)
{
    __shared__ float sA[BT][BK + 1];
    __shared__ float sB[BK][NC];
    __shared__ float sL[BT][NC + 1];
    __shared__ float sN[BT][NE + 1];
    __shared__ float sV1[BT], sV2[BT], sG0[BT], sG1[BT];
    __shared__ int   sI0[BT], sI1[BT];

    const int tid = threadIdx.x;
    const int bt0 = blockIdx.x * BT;
    const int tc = tid & 15;
    const int tr = tid >> 4;

    float acc[2][8];
    #pragma unroll
    for (int i = 0; i < 2; ++i)
        #pragma unroll
        for (int j = 0; j < 8; ++j) acc[i][j] = 0.f;

    const int a_row = tid >> 3;
    const int a_c4  = tid & 7;

    for (int k0 = 0; k0 < D_MODEL; k0 += BK) {
        const float4 av = *(const float4*)(inp + (size_t)(bt0 + a_row) * D_MODEL + k0 + (a_c4 << 2));
        float4 bv[4];
        #pragma unroll
        for (int i = 0; i < 4; ++i) {
            const int v   = tid + (i << 8);
            const int row = v >> 5;
            const int c4  = v & 31;
            const float* src = (c4 < 16)
                ? (w_gate  + (size_t)(k0 + row) * NE + (c4 << 2))
                : (w_noise + (size_t)(k0 + row) * NE + ((c4 - 16) << 2));
            bv[i] = *(const float4*)src;
        }
        __syncthreads();
        sA[a_row][a_c4 * 4 + 0] = av.x;
        sA[a_row][a_c4 * 4 + 1] = av.y;
        sA[a_row][a_c4 * 4 + 2] = av.z;
        sA[a_row][a_c4 * 4 + 3] = av.w;
        #pragma unroll
        for (int i = 0; i < 4; ++i) {
            const int v   = tid + (i << 8);
            const int row = v >> 5;
            const int c4  = v & 31;
            *(float4*)&sB[row][c4 << 2] = bv[i];
        }
        __syncthreads();
        #pragma unroll
        for (int kk = 0; kk < BK; ++kk) {
            const float a0 = sA[tr * 2 + 0][kk];
            const float a1 = sA[tr * 2 + 1][kk];
            const float4 b0 = *(const float4*)&sB[kk][tc * 8 + 0];
            const float4 b1 = *(const float4*)&sB[kk][tc * 8 + 4];
            acc[0][0] = fmaf(a0, b0.x, acc[0][0]); acc[0][1] = fmaf(a0, b0.y, acc[0][1]);
            acc[0][2] = fmaf(a0, b0.z, acc[0][2]); acc[0][3] = fmaf(a0, b0.w, acc[0][3]);
            acc[0][4] = fmaf(a0, b1.x, acc[0][4]); acc[0][5] = fmaf(a0, b1.y, acc[0][5]);
            acc[0][6] = fmaf(a0, b1.z, acc[0][6]); acc[0][7] = fmaf(a0, b1.w, acc[0][7]);
            acc[1][0] = fmaf(a1, b0.x, acc[1][0]); acc[1][1] = fmaf(a1, b0.y, acc[1][1]);
            acc[1][2] = fmaf(a1, b0.z, acc[1][2]); acc[1][3] = fmaf(a1, b0.w, acc[1][3]);
            acc[1][4] = fmaf(a1, b1.x, acc[1][4]); acc[1][5] = fmaf(a1, b1.y, acc[1][5]);
            acc[1][6] = fmaf(a1, b1.z, acc[1][6]); acc[1][7] = fmaf(a1, b1.w, acc[1][7]);
        }
    }

    __syncthreads();
    #pragma unroll
    for (int i = 0; i < 2; ++i)
        #pragma unroll
        for (int j = 0; j < 8; ++j)
            sL[tr * 2 + i][tc * 8 + j] = acc[i][j];

    for (int v = tid; v < BT * NE; v += FBLOCK) {
        const int t = v >> 6, e = v & 63;
        sN[t][e] = noise[(size_t)(bt0 + t) * NE + e];
    }
    __syncthreads();

    if (tid < BT) {
        const int t  = tid;
        const int gt = bt0 + t;
        float v0 = -3.4e38f, v1 = -3.4e38f, v2 = -3.4e38f;
        int   i0 = 0, i1 = 0;
        #pragma unroll 4
        for (int e = 0; e < NE; ++e) {
            const float clean = sL[t][e];
            const float raw   = sL[t][NE + e];
            const float sd    = softplus_f(raw) + 0.01f;
            sL[t][NE + e] = sd;
            const float ny = fmaf(sN[t][e], sd, clean);
            sN[t][e] = ny;
            if (ny > v0)      { v2 = v1; v1 = v0; i1 = i0; v0 = ny; i0 = e; }
            else if (ny > v1) { v2 = v1; v1 = ny; i1 = e; }
            else if (ny > v2) { v2 = ny; }
        }
        const float e1 = expf(v1 - v0);
        const float d  = 1.f + e1;
        const float g0 = 1.f / d;
        const float g1 = e1 / d;
        out[2 * gt + 0] = (float)i0;
        out[2 * gt + 1] = (float)i1;
        out[2 * N_TOKENS + 2 * gt + 0] = g0;
        out[2 * N_TOKENS + 2 * gt + 1] = g1;
        sV1[t] = v1; sV2[t] = v2;
        sI0[t] = i0; sI1[t] = i1;
        sG0[t] = g0; sG1[t] = g1;
    }
    __syncthreads();

    if (tid < NE) {
        const int e = tid;
        float loadsum = 0.f, impsum = 0.f;
        #pragma unroll 4
        for (int t = 0; t < BT; ++t) {
            const float clean = sL[t][e];
            const float sd    = sL[t][NE + e];
            const float ny    = sN[t][e];
            const float thr   = (ny > sV2[t]) ? sV2[t] : sV1[t];
            const float z     = (clean - thr) / sd;
            loadsum += ncdf(z);
            if (sI0[t] == e) impsum += sG0[t];
            if (sI1[t] == e) impsum += sG1[t];
        }
        atomicAdd(&ws[e],      impsum);
        atomicAdd(&ws[NE + e], loadsum);
    }
}

extern "C" void kernel_launch(void* const* d_in, const int* in_sizes, int n_in,
                              void* d_out, int out_size, void* d_ws, size_t ws_size,
                              hipStream_t stream) {
    const float* inp     = (const float*)d_in[0];
    const float* w_gate  = (const float*)d_in[1];
    const float* w_noise = (const float*)d_in[2];
    const float* noise   = (const float*)d_in[3];
    float* out = (float*)d_out;

    float* sums = (float*)((char*)d_ws + WS_SUMS);
    int*   cnt  = (int*)((char*)d_ws + WS_CNT);
    int*   list = (int*)((char*)d_ws + WS_LIST);
    u16*   Bhi  = (u16*)((char*)d_ws + WS_BHI);
    u16*   Blo  = (u16*)((char*)d_ws + WS_BLO);

    if (ws_size >= (size_t)FAST_NEED) {
        k_zero<<<1, 192, 0, stream>>>(sums, cnt);
        k_prep<<<128, 256, 0, stream>>>(w_gate, w_noise, Bhi, Blo);
        k_main<<<N_TOKENS / 64, 512, 0, stream>>>(inp, Bhi, Blo, noise, out, sums, cnt, list);
        k_fix<<<1024, 512, 0, stream>>>(inp, w_gate, w_noise, noise, out, sums, cnt, list);
        k_loss<<<1, 64, 0, stream>>>(sums, out);
    } else {
        k_zero<<<1, 192, 0, stream>>>(sums, nullptr);
        gate_fb<<<N_TOKENS / BT, FBLOCK, 0, stream>>>(inp, w_gate, w_noise, noise, out, sums);
        k_loss<<<1, 64, 0, stream>>>(sums, out);
    }
}

// Round 5
// 563.237 us; speedup vs baseline: 1.8707x; 1.0142x over previous
//
#include <hip/hip_runtime.h>
#include <math.h>

#define N_TOKENS 16384
#define D_MODEL  4096
#define NE       64
#define NC       128
#define DELTA    0.005f
#define LIST_CAP 16384

// ---- ws layout (bytes) ---- (proven: ws_size >= FAST_NEED)
#define WS_SUMS   0          // 128 f32
#define WS_CNT    512        // int
#define WS_LIST   4096       // 16384 int
#define WS_BHI    131072     // 1 MB bf16 hi limbs [128 kc][4 kg][128 n][8 j]
#define WS_BLO    1179648    // 1 MB bf16 lo limbs, same layout
#define FAST_NEED 2228224

typedef unsigned short u16;
typedef __attribute__((ext_vector_type(8))) short short8;   // 8 bf16
typedef __attribute__((ext_vector_type(4))) float f32x4;

#define MFMA16 __builtin_amdgcn_mfma_f32_16x16x32_bf16

typedef const __attribute__((address_space(1))) void cg_void;
typedef __attribute__((address_space(3))) void lds_void;
__device__ __forceinline__ void gll16(const void* g, void* l) {
    __builtin_amdgcn_global_load_lds((cg_void*)g, (lds_void*)l, 16, 0, 0);
}

__device__ __forceinline__ u16 f2bf(float x) {
    unsigned u = __float_as_uint(x);
    return (u16)((u + 0x7FFFu + ((u >> 16) & 1u)) >> 16);
}
__device__ __forceinline__ float bf2f(u16 h) { return __uint_as_float(((unsigned)h) << 16); }
__device__ __forceinline__ float softplus_f(float x) {
    return (x > 0.f) ? x + log1pf(expf(-x)) : log1pf(expf(x));
}
__device__ __forceinline__ float ncdf(float z) { return 0.5f * erfcf(-z * 0.70710678118654752f); }

__global__ void k_zero(float* __restrict__ sums, int* __restrict__ cnt) {
    if (threadIdx.x < 128) sums[threadIdx.x] = 0.f;
    if (cnt != nullptr && threadIdx.x == 128) *cnt = 0;
}

// B limbs, k-major swizzle: elem offset = kc*4096 + kg*1024 + n*8 + j
// (k = kc*32 + kg*8 + j). One 8KB chunk per kc per limb, in exact gll16 lane order.
__global__ __launch_bounds__(256) void k_prep(const float* __restrict__ wg, const float* __restrict__ wn,
                                              u16* __restrict__ Bhi, u16* __restrict__ Blo) {
    __shared__ float sW[32 * 129];
    const int kc = blockIdx.x, tid = threadIdx.x;
    #pragma unroll
    for (int i = 0; i < 16; ++i) {
        const int v = tid + 256 * i;          // 4096 elems
        const int kk = v >> 7, n = v & 127;
        const int k = kc * 32 + kk;
        const float x = (n < 64) ? wg[(size_t)k * 64 + n] : wn[(size_t)k * 64 + n - 64];
        sW[kk * 129 + n] = x;
    }
    __syncthreads();
    #pragma unroll
    for (int i = 0; i < 16; ++i) {
        const int o   = tid + 256 * i;        // o = kg*1024 + n*8 + j
        const int kg  = o >> 10;
        const int rem = o & 1023;
        const int n   = rem >> 3, j = rem & 7;
        const int kk  = kg * 8 + j;
        const float x = sW[kk * 129 + n];
        const u16 h = f2bf(x);
        Bhi[(size_t)kc * 4096 + o] = h;
        Blo[(size_t)kc * 4096 + o] = f2bf(x - bf2f(h));
    }
}

// Fused split-bf16 GEMM + gating epilogue.
// 32 tokens/block, grid 512 (2 blocks/CU), 512 thr = 8 waves.
// wave w: rows (w&1)*16, cols (w>>1)*32. BK=32, 128 chunks, single-barrier dbuf.
// LDS tiles k-major: A [kg4][row32][8k], B [kg4][n128][8k] -> conflict-free b128 frag reads.
__global__ __launch_bounds__(512, 2) void k_main(
    const float* __restrict__ inp, const u16* __restrict__ Bhi, const u16* __restrict__ Blo,
    const float* __restrict__ noise, float* __restrict__ out, float* __restrict__ sums,
    int* __restrict__ cnt, int* __restrict__ list)
{
    __shared__ __align__(16) char smem[40960];
    // buffer b at smem + b*20480: Ah 2KB @0, Al @2048, Bh 8KB @4096, Bl @12288
#define AHB(b) (smem + (b) * 20480)
#define ALB(b) (smem + (b) * 20480 + 2048)
#define BHB(b) (smem + (b) * 20480 + 4096)
#define BLB(b) (smem + (b) * 20480 + 12288)

    const int tid = threadIdx.x;
    const int l   = tid & 63;
    const int w   = tid >> 6;         // 0..7
    const int t0  = blockIdx.x * 32;
    const int m   = l & 15;
    const int q   = l >> 4;           // k-group 0..3
    const int r0  = (w & 1) * 16;     // wave row base
    const int c0  = (w >> 1) * 32;    // wave col base

    f32x4 acc[2];
    #pragma unroll
    for (int j = 0; j < 2; ++j)
        #pragma unroll
        for (int r = 0; r < 4; ++r) acc[j][r] = 0.f;

    // A staging: 32 rows x 16 float2; thread -> (row, k2)
    const int arow = tid >> 4, ak2 = tid & 15;
    const float* aptr = inp + (size_t)(t0 + arow) * D_MODEL + ak2 * 2;
    const int akg = ak2 >> 2;                 // (ak2*2)>>3
    const int awoff = akg * 512 + arow * 16 + ((ak2 & 3) * 2) * 2;   // byte offset in A tile

    // B gll16: wave-uniform LDS base w*1024; per-lane global offset w*512 + l*8 elems
    const size_t bgoff = (size_t)w * 512 + (size_t)l * 8;
    const int bloff = w * 1024;

    // ---- prologue: stage chunk 0 into buffer 0 ----
    {
        const float2 av = *(const float2*)aptr;
        gll16(Bhi + bgoff, BHB(0) + bloff);
        gll16(Blo + bgoff, BLB(0) + bloff);
        const float x0 = av.x, x1 = av.y;
        const unsigned u0 = __float_as_uint(x0), u1 = __float_as_uint(x1);
        const u16 h0 = (u16)(u0 >> 16), h1 = (u16)(u1 >> 16);
        const u16 l0 = f2bf(x0 - __uint_as_float(u0 & 0xFFFF0000u));
        const u16 l1 = f2bf(x1 - __uint_as_float(u1 & 0xFFFF0000u));
        *(unsigned*)(AHB(0) + awoff) = (unsigned)h0 | ((unsigned)h1 << 16);
        *(unsigned*)(ALB(0) + awoff) = (unsigned)l0 | ((unsigned)l1 << 16);
    }

    for (int c = 0; c < 128; ++c) {
        const int rc = c & 1, nb = rc ^ 1;
        __syncthreads();   // buffer rc complete (vmcnt: B via gll16, lgkm: A writes)

        float2 avn;
        if (c < 127) {
            avn = *(const float2*)(aptr + (c + 1) * 32);
            const size_t go = (size_t)(c + 1) * 4096 + bgoff;
            gll16(Bhi + go, BHB(nb) + bloff);
            gll16(Blo + go, BLB(nb) + bloff);
        }

        // conflict-free frag reads: each b128 covers 1024 consecutive bytes across the wave
        const short8 ah = *(const short8*)(AHB(rc) + q * 512 + (r0 + m) * 16);
        const short8 al = *(const short8*)(ALB(rc) + q * 512 + (r0 + m) * 16);
        short8 bh[2], bl[2];
        #pragma unroll
        for (int jf = 0; jf < 2; ++jf) {
            bh[jf] = *(const short8*)(BHB(rc) + q * 2048 + (c0 + jf * 16 + m) * 16);
            bl[jf] = *(const short8*)(BLB(rc) + q * 2048 + (c0 + jf * 16 + m) * 16);
        }
        #pragma unroll
        for (int jf = 0; jf < 2; ++jf) {
            acc[jf] = MFMA16(ah, bh[jf], acc[jf], 0, 0, 0);
            acc[jf] = MFMA16(ah, bl[jf], acc[jf], 0, 0, 0);
            acc[jf] = MFMA16(al, bh[jf], acc[jf], 0, 0, 0);
        }

        if (c < 127) {
            const float x0 = avn.x, x1 = avn.y;
            const unsigned u0 = __float_as_uint(x0), u1 = __float_as_uint(x1);
            const u16 h0 = (u16)(u0 >> 16), h1 = (u16)(u1 >> 16);
            const u16 l0 = f2bf(x0 - __uint_as_float(u0 & 0xFFFF0000u));
            const u16 l1 = f2bf(x1 - __uint_as_float(u1 & 0xFFFF0000u));
            *(unsigned*)(AHB(nb) + awoff) = (unsigned)h0 | ((unsigned)h1 << 16);
            *(unsigned*)(ALB(nb) + awoff) = (unsigned)l0 | ((unsigned)l1 << 16);
        }
    }
    __syncthreads();   // GEMM LDS dead; overlay epilogue arrays

    float* const sL  = (float*)(smem);          // [32][132] = 16896 B
    float* const sN  = (float*)(smem + 16896);  // [32][68]  = 8704 B
    float* const sV1 = (float*)(smem + 25600);
    float* const sV2 = (float*)(smem + 25728);
    float* const sG0 = (float*)(smem + 25856);
    float* const sG1 = (float*)(smem + 25984);
    int*   const sI0 = (int*)(smem + 26112);
    int*   const sI1 = (int*)(smem + 26240);
    int*   const sRk = (int*)(smem + 26368);

    // C/D layout (m89-verified): col = lane&15, row = (lane>>4)*4 + reg
    #pragma unroll
    for (int jf = 0; jf < 2; ++jf)
        #pragma unroll
        for (int r = 0; r < 4; ++r)
            sL[(r0 + q * 4 + r) * 132 + c0 + jf * 16 + m] = acc[jf][r];

    {   // noise: 32x64 = 512 float4, one per thread
        const int t = tid >> 4, e4 = tid & 15;
        *(float4*)&sN[t * 68 + e4 * 4] = *(const float4*)(noise + (size_t)(t0 + t) * NE + e4 * 4);
    }
    __syncthreads();

    if (tid < 32) {
        const int t = tid, gt = t0 + t;
        float v0 = -3.4e38f, v1 = -3.4e38f, v2 = -3.4e38f;
        int i0 = 0, i1 = 0;
        #pragma unroll 4
        for (int e = 0; e < NE; ++e) {
            const float clean = sL[t * 132 + e];
            const float sd    = softplus_f(sL[t * 132 + 64 + e]) + 0.01f;
            const float ny    = fmaf(sN[t * 68 + e], sd, clean);
            if (ny > v0)      { v2 = v1; v1 = v0; i1 = i0; v0 = ny; i0 = e; }
            else if (ny > v1) { v2 = v1; v1 = ny; i1 = e; }
            else if (ny > v2) { v2 = ny; }
        }
        const float e1 = expf(v1 - v0);
        const float d  = 1.f + e1;
        const float g0 = 1.f / d, g1 = e1 / d;
        out[2 * gt + 0] = (float)i0;
        out[2 * gt + 1] = (float)i1;
        out[2 * N_TOKENS + 2 * gt + 0] = g0;
        out[2 * N_TOKENS + 2 * gt + 1] = g1;
        const int risky = ((v0 - v1) < DELTA) || ((v1 - v2) < DELTA);
        sRk[t] = risky;
        if (risky) {
            const int idx = atomicAdd(cnt, 1);
            if (idx < LIST_CAP) list[idx] = gt;
        }
        sV1[t] = v1; sV2[t] = v2; sI0[t] = i0; sI1[t] = i1; sG0[t] = g0; sG1[t] = g1;
    }
    __syncthreads();

    if (tid < 128) {
        const int e = tid & 63, h = tid >> 6;
        float loadsum = 0.f, impsum = 0.f;
        #pragma unroll 4
        for (int t = h * 16; t < h * 16 + 16; ++t) {
            if (sRk[t]) continue;
            const float clean = sL[t * 132 + e];
            const float sd    = softplus_f(sL[t * 132 + 64 + e]) + 0.01f;
            const float ny    = fmaf(sN[t * 68 + e], sd, clean);
            const float thr   = (ny > sV2[t]) ? sV2[t] : sV1[t];
            loadsum += ncdf((clean - thr) / sd);
            if (sI0[t] == e) impsum += sG0[t];
            if (sI1[t] == e) impsum += sG1[t];
        }
        atomicAdd(&sums[e], impsum);
        atomicAdd(&sums[64 + e], loadsum);
    }
}

// exact fp32 recompute for risky (near-tie) tokens; 512 thr, K split x4
__global__ __launch_bounds__(512) void k_fix(const float* __restrict__ inp,
                                             const float* __restrict__ wg,
                                             const float* __restrict__ wn,
                                             const float* __restrict__ noise,
                                             float* __restrict__ out,
                                             float* __restrict__ sums,
                                             const int* __restrict__ cnt,
                                             const int* __restrict__ list) {
    __shared__ float sRow[D_MODEL];
    __shared__ float sP[512];
    __shared__ float sLg[NC];
    __shared__ float fv1, fv2;

    const int tid = threadIdx.x;
    int n = *cnt;
    if (n > LIST_CAP) n = LIST_CAP;

    for (int it = blockIdx.x; it < n; it += gridDim.x) {
        const int tok = list[it];
        __syncthreads();
        #pragma unroll
        for (int i = 0; i < 2; ++i)
            *(float4*)&sRow[(tid + 512 * i) * 4] = *(const float4*)(inp + (size_t)tok * D_MODEL + (tid + 512 * i) * 4);
        __syncthreads();

        const int c = tid & 127, h = tid >> 7;
        const float* wcol = (c < 64) ? (wg + c) : (wn + c - 64);
        float s = 0.f;
        #pragma unroll 16
        for (int k = h * 1024; k < h * 1024 + 1024; ++k)
            s = fmaf(sRow[k], wcol[(size_t)k * 64], s);
        sP[tid] = s;
        __syncthreads();
        if (tid < 128) sLg[tid] = sP[tid] + sP[tid + 128] + sP[tid + 256] + sP[tid + 384];
        __syncthreads();

        if (tid == 0) {
            float v0 = -3.4e38f, v1 = -3.4e38f, v2 = -3.4e38f;
            int i0 = 0, i1 = 0;
            for (int e = 0; e < NE; ++e) {
                const float sd = softplus_f(sLg[64 + e]) + 0.01f;
                const float ny = fmaf(noise[(size_t)tok * NE + e], sd, sLg[e]);
                if (ny > v0)      { v2 = v1; v1 = v0; i1 = i0; v0 = ny; i0 = e; }
                else if (ny > v1) { v2 = v1; v1 = ny; i1 = e; }
                else if (ny > v2) { v2 = ny; }
            }
            const float e1 = expf(v1 - v0);
            const float d  = 1.f + e1;
            const float g0 = 1.f / d, g1 = e1 / d;
            out[2 * tok + 0] = (float)i0;
            out[2 * tok + 1] = (float)i1;
            out[2 * N_TOKENS + 2 * tok + 0] = g0;
            out[2 * N_TOKENS + 2 * tok + 1] = g1;
            atomicAdd(&sums[i0], g0);
            atomicAdd(&sums[i1], g1);
            fv1 = v1; fv2 = v2;
        }
        __syncthreads();
        if (tid < 64) {
            const int e = tid;
            const float clean = sLg[e];
            const float sd    = softplus_f(sLg[64 + e]) + 0.01f;
            const float ny    = fmaf(noise[(size_t)tok * NE + e], sd, clean);
            const float thr   = (ny > fv2) ? fv2 : fv1;
            atomicAdd(&sums[64 + e], ncdf((clean - thr) / sd));
        }
    }
}

__global__ void k_loss(const float* __restrict__ sums, float* __restrict__ out) {
    const int l = threadIdx.x;
    const float x = sums[l];
    const float y = sums[64 + l];
    float sx = x, sy = y;
    #pragma unroll
    for (int off = 32; off >= 1; off >>= 1) { sx += __shfl_xor(sx, off); sy += __shfl_xor(sy, off); }
    const float mx = sx / 64.f, my = sy / 64.f;
    const float dx = x - mx, dy = y - my;
    float vx = dx * dx, vy = dy * dy;
    #pragma unroll
    for (int off = 32; off >= 1; off >>= 1) { vx += __shfl_xor(vx, off); vy += __shfl_xor(vy, off); }
    if (l == 0)
        out[2 * N_TOKENS * 2] = (vx / 63.f) / (mx * mx + 1e-10f) + (vy / 63.f) / (my * my + 1e-10f);
}

// ---------- fallback: round-1 kernel, verbatim (uses only 512 B of ws) ----------
#define BT 32
#define BK 32
#define FBLOCK 256
__global__ __launch_bounds__(FBLOCK) void gate_fb(
    const float* __restrict__ inp, const float* __restrict__ w_gate,
    const float* __restrict__ w_noise, const float* __restrict__ noise,
    float* __restrict__ out, float* __restrict__ ws)
{
    __shared__ float sA[BT][BK + 1];
    __shared__ float sB[BK][NC];
    __shared__ float sL[BT][NC + 1];
    __shared__ float sN[BT][NE + 1];
    __shared__ float sV1[BT], sV2[BT], sG0[BT], sG1[BT];
    __shared__ int   sI0[BT], sI1[BT];

    const int tid = threadIdx.x;
    const int bt0 = blockIdx.x * BT;
    const int tc = tid & 15;
    const int tr = tid >> 4;

    float acc[2][8];
    #pragma unroll
    for (int i = 0; i < 2; ++i)
        #pragma unroll
        for (int j = 0; j < 8; ++j) acc[i][j] = 0.f;

    const int a_row = tid >> 3;
    const int a_c4  = tid & 7;

    for (int k0 = 0; k0 < D_MODEL; k0 += BK) {
        const float4 av = *(const float4*)(inp + (size_t)(bt0 + a_row) * D_MODEL + k0 + (a_c4 << 2));
        float4 bv[4];
        #pragma unroll
        for (int i = 0; i < 4; ++i) {
            const int v   = tid + (i << 8);
            const int row = v >> 5;
            const int c4  = v & 31;
            const float* src = (c4 < 16)
                ? (w_gate  + (size_t)(k0 + row) * NE + (c4 << 2))
                : (w_noise + (size_t)(k0 + row) * NE + ((c4 - 16) << 2));
            bv[i] = *(const float4*)src;
        }
        __syncthreads();
        sA[a_row][a_c4 * 4 + 0] = av.x;
        sA[a_row][a_c4 * 4 + 1] = av.y;
        sA[a_row][a_c4 * 4 + 2] = av.z;
        sA[a_row][a_c4 * 4 + 3] = av.w;
        #pragma unroll
        for (int i = 0; i < 4; ++i) {
            const int v   = tid + (i << 8);
            const int row = v >> 5;
            const int c4  = v & 31;
            *(float4*)&sB[row][c4 << 2] = bv[i];
        }
        __syncthreads();
        #pragma unroll
        for (int kk = 0; kk < BK; ++kk) {
            const float a0 = sA[tr * 2 + 0][kk];
            const float a1 = sA[tr * 2 + 1][kk];
            const float4 b0 = *(const float4*)&sB[kk][tc * 8 + 0];
            const float4 b1 = *(const float4*)&sB[kk][tc * 8 + 4];
            acc[0][0] = fmaf(a0, b0.x, acc[0][0]); acc[0][1] = fmaf(a0, b0.y, acc[0][1]);
            acc[0][2] = fmaf(a0, b0.z, acc[0][2]); acc[0][3] = fmaf(a0, b0.w, acc[0][3]);
            acc[0][4] = fmaf(a0, b1.x, acc[0][4]); acc[0][5] = fmaf(a0, b1.y, acc[0][5]);
            acc[0][6] = fmaf(a0, b1.z, acc[0][6]); acc[0][7] = fmaf(a0, b1.w, acc[0][7]);
            acc[1][0] = fmaf(a1, b0.x, acc[1][0]); acc[1][1] = fmaf(a1, b0.y, acc[1][1]);
            acc[1][2] = fmaf(a1, b0.z, acc[1][2]); acc[1][3] = fmaf(a1, b0.w, acc[1][3]);
            acc[1][4] = fmaf(a1, b1.x, acc[1][4]); acc[1][5] = fmaf(a1, b1.y, acc[1][5]);
            acc[1][6] = fmaf(a1, b1.z, acc[1][6]); acc[1][7] = fmaf(a1, b1.w, acc[1][7]);
        }
    }

    __syncthreads();
    #pragma unroll
    for (int i = 0; i < 2; ++i)
        #pragma unroll
        for (int j = 0; j < 8; ++j)
            sL[tr * 2 + i][tc * 8 + j] = acc[i][j];

    for (int v = tid; v < BT * NE; v += FBLOCK) {
        const int t = v >> 6, e = v & 63;
        sN[t][e] = noise[(size_t)(bt0 + t) * NE + e];
    }
    __syncthreads();

    if (tid < BT) {
        const int t  = tid;
        const int gt = bt0 + t;
        float v0 = -3.4e38f, v1 = -3.4e38f, v2 = -3.4e38f;
        int   i0 = 0, i1 = 0;
        #pragma unroll 4
        for (int e = 0; e < NE; ++e) {
            const float clean = sL[t][e];
            const float raw   = sL[t][NE + e];
            const float sd    = softplus_f(raw) + 0.01f;
            sL[t][NE + e] = sd;
            const float ny = fmaf(sN[t][e], sd, clean);
            sN[t][e] = ny;
            if (ny > v0)      { v2 = v1; v1 = v0; i1 = i0; v0 = ny; i0 = e; }
            else if (ny > v1) { v2 = v1; v1 = ny; i1 = e; }
            else if (ny > v2) { v2 = ny; }
        }
        const float e1 = expf(v1 - v0);
        const float d  = 1.f + e1;
        const float g0 = 1.f / d;
        const float g1 = e1 / d;
        out[2 * gt + 0] = (float)i0;
        out[2 * gt + 1] = (float)i1;
        out[2 * N_TOKENS + 2 * gt + 0] = g0;
        out[2 * N_TOKENS + 2 * gt + 1] = g1;
        sV1[t] = v1; sV2[t] = v2;
        sI0[t] = i0; sI1[t] = i1;
        sG0[t] = g0; sG1[t] = g1;
    }
    __syncthreads();

    if (tid < NE) {
        const int e = tid;
        float loadsum = 0.f, impsum = 0.f;
        #pragma unroll 4
        for (int t = 0; t < BT; ++t) {
            const float clean = sL[t][e];
            const float sd    = sL[t][NE + e];
            const float ny    = sN[t][e];
            const float thr   = (ny > sV2[t]) ? sV2[t] : sV1[t];
            const float z     = (clean - thr) / sd;
            loadsum += ncdf(z);
            if (sI0[t] == e) impsum += sG0[t];
            if (sI1[t] == e) impsum += sG1[t];
        }
        atomicAdd(&ws[e],      impsum);
        atomicAdd(&ws[NE + e], loadsum);
    }
}

extern "C" void kernel_launch(void* const* d_in, const int* in_sizes, int n_in,
                              void* d_out, int out_size, void* d_ws, size_t ws_size,
                              hipStream_t stream) {
    const float* inp     = (const float*)d_in[0];
    const float* w_gate  = (const float*)d_in[1];
    const float* w_noise = (const float*)d_in[2];
    const float* noise   = (const float*)d_in[3];
    float* out = (float*)d_out;

    float* sums = (float*)((char*)d_ws + WS_SUMS);
    int*   cnt  = (int*)((char*)d_ws + WS_CNT);
    int*   list = (int*)((char*)d_ws + WS_LIST);
    u16*   Bhi  = (u16*)((char*)d_ws + WS_BHI);
    u16*   Blo  = (u16*)((char*)d_ws + WS_BLO);

    if (ws_size >= (size_t)FAST_NEED) {
        k_zero<<<1, 192, 0, stream>>>(sums, cnt);
        k_prep<<<128, 256, 0, stream>>>(w_gate, w_noise, Bhi, Blo);
        k_main<<<N_TOKENS / 32, 512, 0, stream>>>(inp, Bhi, Blo, noise, out, sums, cnt, list);
        k_fix<<<1024, 512, 0, stream>>>(inp, w_gate, w_noise, noise, out, sums, cnt, list);
        k_loss<<<1, 64, 0, stream>>>(sums, out);
    } else {
        k_zero<<<1, 192, 0, stream>>>(sums, nullptr);
        gate_fb<<<N_TOKENS / BT, FBLOCK, 0, stream>>>(inp, w_gate, w_noise, noise, out, sums);
        k_loss<<<1, 64, 0, stream>>>(sums, out);
    }
}